// Round 3
// baseline (6658.380 us; speedup 1.0000x reference)
//
#include <hip/hip_runtime.h>
#include <hip/hip_bf16.h>

typedef float f32x4 __attribute__((ext_vector_type(4)));
typedef short short8 __attribute__((ext_vector_type(8)));   // 8 bf16 = MFMA A/B frag

__device__ __forceinline__ short f2b(float x) {
    union { __hip_bfloat16 b; short s; } u;
    u.b = __float2bfloat16(x);   // round-to-nearest-even
    return u.s;
}

// Fused VLSTM cell:
//   x = [in|h|z] @ [Wk;Wr;Wl] + bias  (M=4096, Neff=8192, K=6144, fp32 in, bf16 MFMA)
//   h = hs(x_o) * tanh( hs(x_f)*c_tm1 + hs(x_i)*tanh(x_c) )
//
// Block tile: 128 rows x 64 h-cols (= 4 gates -> 128x256 eff GEMM tile), 4 waves.
// Both A and B staged in LDS with k-CONTIGUOUS rows ([row][k] / [col][k], stride 40)
// so A-frag and B-frag reads are the same 8-contiguous-k ds_read_b128 pattern:
// correctness is invariant to the MFMA's internal slot->k permutation (A,B mirrored).
// B is transposed during staging: scalar global loads (coalesced across lanes along n),
// pack 8 k-values -> one ds_write_b128.
__global__ __launch_bounds__(256, 2)
void vlstm_fused(const float* __restrict__ xin, const float* __restrict__ h_tm1,
                 const float* __restrict__ c_tm1, const float* __restrict__ z_tm1,
                 const float* __restrict__ Wk, const float* __restrict__ Wr,
                 const float* __restrict__ Wl, const float* __restrict__ bias,
                 float* __restrict__ out)
{
    __shared__ __align__(16) unsigned short Alds[2][128][40];   // 20 KB
    __shared__ __align__(16) unsigned short Blds[2][256][40];   // 40 KB

    const int tid  = threadIdx.x;
    const int wave = tid >> 6, lane = tid & 63;
    const int wr = wave >> 1, wc = wave & 1;       // wave 2x2 over (m, h-cols)
    const int l15 = lane & 15, q = lane >> 4;

    // XCD-bijective swizzle (1024 % 8 == 0); n fast => A panel L2-resident per XCD.
    const int bid = (int)blockIdx.x;
    const int swz = (bid & 7) * 128 + (bid >> 3);
    const int bm = swz >> 5, bn = swz & 31;
    const int row0 = bm * 128, col0 = bn * 64;

    // A staging: 2 threads/row, 16 consecutive k each.
    const int arow = tid >> 1, kh = tid & 1;
    // B staging: thread t owns eff-col c_block = t (gate = t>>6, col = t&63),
    // loads 4 k-strips of 8 (scalar loads, coalesced across consecutive t).
    const long bg_off = (long)(tid >> 6) * 2048 + col0 + (tid & 63);

    f32x4 acc[4][4][2];   // [gate][m-frag][n-frag]
    #pragma unroll
    for (int g = 0; g < 4; ++g)
        #pragma unroll
        for (int mi = 0; mi < 4; ++mi)
            #pragma unroll
            for (int ni = 0; ni < 2; ++ni)
                acc[g][mi][ni] = (f32x4){0.f, 0.f, 0.f, 0.f};

    f32x4 sa[4];    // A staging regs (16 fp32)
    float sb[32];   // B staging regs (32 fp32, fully unrolled const-indexed)

    auto do_loads = [&](int kn) {
        const int s  = kn >> 6;            // source: 0=in/Wk 1=h/Wr 2=z/Wl
        const int kl = (kn & 63) << 5;     // k within source
        const float* Ap = (s == 0) ? xin : (s == 1) ? h_tm1 : z_tm1;
        const float* Bp = (s == 0) ? Wk  : (s == 1) ? Wr    : Wl;
        const float* ap = Ap + (long)(row0 + arow) * 2048 + kl + kh * 16;
        #pragma unroll
        for (int i = 0; i < 4; ++i) sa[i] = ((const f32x4*)ap)[i];
        const float* bp = Bp + (long)kl * 8192 + bg_off;
        #pragma unroll
        for (int kk = 0; kk < 32; ++kk)
            sb[kk] = bp[(long)kk * 8192];
    };

    auto do_store = [&](int buf) {
        short8 p0, p1;
        #pragma unroll
        for (int j = 0; j < 4; ++j) {
            p0[j] = f2b(sa[0][j]); p0[4 + j] = f2b(sa[1][j]);
            p1[j] = f2b(sa[2][j]); p1[4 + j] = f2b(sa[3][j]);
        }
        *(short8*)&Alds[buf][arow][kh * 16]     = p0;
        *(short8*)&Alds[buf][arow][kh * 16 + 8] = p1;
        #pragma unroll
        for (int ks = 0; ks < 4; ++ks) {
            short8 pb;
            #pragma unroll
            for (int j = 0; j < 8; ++j) pb[j] = f2b(sb[ks * 8 + j]);
            *(short8*)&Blds[buf][tid][ks * 8] = pb;   // col-row c_block = tid
        }
    };

    do_loads(0);
    do_store(0);
    __syncthreads();

    for (int kt = 0; kt < 192; ++kt) {
        const int cur = kt & 1;
        if (kt + 1 < 192) do_loads(kt + 1);   // issue next-step globals early

        // A frags: row = wr*64 + mi*16 + l15, 8 contiguous k at q*8.
        short8 afr[4];
        #pragma unroll
        for (int mi = 0; mi < 4; ++mi)
            afr[mi] = *(const short8*)&Alds[cur][wr * 64 + mi * 16 + l15][q * 8];

        // B frags: identical pattern on the transposed-staged tile.
        short8 bfr[4][2];
        #pragma unroll
        for (int g = 0; g < 4; ++g)
            #pragma unroll
            for (int ni = 0; ni < 2; ++ni)
                bfr[g][ni] = *(const short8*)
                    &Blds[cur][g * 64 + wc * 32 + ni * 16 + l15][q * 8];

        #pragma unroll
        for (int g = 0; g < 4; ++g)
            #pragma unroll
            for (int ni = 0; ni < 2; ++ni)
                #pragma unroll
                for (int mi = 0; mi < 4; ++mi)
                    acc[g][mi][ni] = __builtin_amdgcn_mfma_f32_16x16x32_bf16(
                        afr[mi], bfr[g][ni], acc[g][mi][ni], 0, 0, 0);

        if (kt + 1 < 192) do_store(cur ^ 1);
        __syncthreads();   // single barrier/step: reads(cur) before it, writes(cur^1) ok
    }

    // Epilogue: C/D layout col = l15, row = q*4 + reg (m89/m91 HW-verified).
    #pragma unroll
    for (int ni = 0; ni < 2; ++ni) {
        const int col = col0 + wc * 32 + ni * 16 + l15;
        const float bi  = bias[col];
        const float bf_ = bias[2048 + col];
        const float bc  = bias[4096 + col];
        const float bo  = bias[6144 + col];
        #pragma unroll
        for (int mi = 0; mi < 4; ++mi) {
            const int rbase = row0 + wr * 64 + mi * 16 + q * 4;
            #pragma unroll
            for (int rr = 0; rr < 4; ++rr) {
                const int row = rbase + rr;
                const float xi = acc[0][mi][ni][rr] + bi;
                const float xf = acc[1][mi][ni][rr] + bf_;
                const float xc = acc[2][mi][ni][rr] + bc;
                const float xo = acc[3][mi][ni][rr] + bo;
                const float ig = __builtin_amdgcn_fmed3f(0.2f * xi + 0.5f, 0.f, 1.f);
                const float fg = __builtin_amdgcn_fmed3f(0.2f * xf + 0.5f, 0.f, 1.f);
                const float og = __builtin_amdgcn_fmed3f(0.2f * xo + 0.5f, 0.f, 1.f);
                const float cp = c_tm1[(long)row * 2048 + col];
                const float cc = fg * cp + ig * tanhf(xc);
                out[(long)row * 2048 + col] = og * tanhf(cc);
            }
        }
    }
}

extern "C" void kernel_launch(void* const* d_in, const int* in_sizes, int n_in,
                              void* d_out, int out_size, void* d_ws, size_t ws_size,
                              hipStream_t stream) {
    const float* xin  = (const float*)d_in[0];
    const float* h1   = (const float*)d_in[1];
    const float* c1   = (const float*)d_in[2];
    const float* z1   = (const float*)d_in[3];
    const float* Wk   = (const float*)d_in[4];
    const float* Wr   = (const float*)d_in[5];
    const float* Wl   = (const float*)d_in[6];
    const float* bias = (const float*)d_in[7];
    float* out = (float*)d_out;
    (void)in_sizes; (void)n_in; (void)out_size; (void)d_ws; (void)ws_size;

    vlstm_fused<<<dim3(1024), dim3(256), 0, stream>>>(xin, h1, c1, z1, Wk, Wr, Wl, bias, out);
}

// Round 4
// 971.546 us; speedup vs baseline: 6.8534x; 6.8534x over previous
//
#include <hip/hip_runtime.h>
#include <hip/hip_bf16.h>

typedef float f32x4 __attribute__((ext_vector_type(4)));
typedef short short8 __attribute__((ext_vector_type(8)));   // 8 bf16 = MFMA A/B frag

__device__ __forceinline__ short f2b(float x) {
    union { __hip_bfloat16 b; short s; } u;
    u.b = __float2bfloat16(x);   // round-to-nearest-even
    return u.s;
}

// Fused VLSTM cell:
//   x = [in|h|z] @ [Wk;Wr;Wl] + bias  (M=4096, Neff=8192, K=6144, fp32 in, bf16 MFMA)
//   h = hs(x_o) * tanh( hs(x_f)*c_tm1 + hs(x_i)*tanh(x_c) )
//
// Identical structure/numerics to round-3 (passed, absmax 1.73e-2), but the staging
// lambdas are replaced by macros: round-3's rocprof showed VGPR_Count=104 +
// WRITE_SIZE=9.7GB => the acc[4][4][2] aggregate was spilled to scratch (lambda
// bodies not inlined -> alloca). Macros guarantee textual inlining.
__global__ __launch_bounds__(256, 2)
void vlstm_fused(const float* __restrict__ xin, const float* __restrict__ h_tm1,
                 const float* __restrict__ c_tm1, const float* __restrict__ z_tm1,
                 const float* __restrict__ Wk, const float* __restrict__ Wr,
                 const float* __restrict__ Wl, const float* __restrict__ bias,
                 float* __restrict__ out)
{
    __shared__ __align__(16) unsigned short Alds[2][128][40];   // 20 KB
    __shared__ __align__(16) unsigned short Blds[2][256][40];   // 40 KB

    const int tid  = threadIdx.x;
    const int wave = tid >> 6, lane = tid & 63;
    const int wr = wave >> 1, wc = wave & 1;       // wave 2x2 over (m, h-cols)
    const int l15 = lane & 15, q = lane >> 4;

    // XCD-bijective swizzle (1024 % 8 == 0); n fast => A panel L2-resident per XCD.
    const int bid = (int)blockIdx.x;
    const int swz = (bid & 7) * 128 + (bid >> 3);
    const int bm = swz >> 5, bn = swz & 31;
    const int row0 = bm * 128, col0 = bn * 64;

    // A staging: 2 threads/row, 16 consecutive k each.
    const int arow = tid >> 1, kh = tid & 1;
    // B staging: thread t owns eff-col t (gate = t>>6, col = t&63), 32 k scalars.
    const long bg_off = (long)(tid >> 6) * 2048 + col0 + (tid & 63);

    f32x4 acc[4][4][2];   // [gate][m-frag][n-frag]
    #pragma unroll
    for (int g = 0; g < 4; ++g)
        #pragma unroll
        for (int mi = 0; mi < 4; ++mi)
            #pragma unroll
            for (int ni = 0; ni < 2; ++ni)
                acc[g][mi][ni] = (f32x4){0.f, 0.f, 0.f, 0.f};

    f32x4 sa[4];    // A staging regs (16 fp32)
    float sb[32];   // B staging regs (32 fp32)

#define DO_LOADS(kn_) do {                                                      \
    const int s_  = (kn_) >> 6;            /* 0=in/Wk 1=h/Wr 2=z/Wl */          \
    const int kl_ = ((kn_) & 63) << 5;                                          \
    const float* Ap_ = (s_ == 0) ? xin : (s_ == 1) ? h_tm1 : z_tm1;             \
    const float* Bp_ = (s_ == 0) ? Wk  : (s_ == 1) ? Wr    : Wl;                \
    const float* ap_ = Ap_ + (long)(row0 + arow) * 2048 + kl_ + kh * 16;        \
    _Pragma("unroll")                                                           \
    for (int i_ = 0; i_ < 4; ++i_) sa[i_] = ((const f32x4*)ap_)[i_];            \
    const float* bp_ = Bp_ + (long)kl_ * 8192 + bg_off;                         \
    _Pragma("unroll")                                                           \
    for (int kk_ = 0; kk_ < 32; ++kk_) sb[kk_] = bp_[(long)kk_ * 8192];         \
} while (0)

#define DO_STORE(buf_) do {                                                     \
    short8 p0_, p1_;                                                            \
    _Pragma("unroll")                                                           \
    for (int j_ = 0; j_ < 4; ++j_) {                                            \
        p0_[j_] = f2b(sa[0][j_]); p0_[4 + j_] = f2b(sa[1][j_]);                 \
        p1_[j_] = f2b(sa[2][j_]); p1_[4 + j_] = f2b(sa[3][j_]);                 \
    }                                                                           \
    *(short8*)&Alds[buf_][arow][kh * 16]     = p0_;                             \
    *(short8*)&Alds[buf_][arow][kh * 16 + 8] = p1_;                             \
    _Pragma("unroll")                                                           \
    for (int ks_ = 0; ks_ < 4; ++ks_) {                                         \
        short8 pb_;                                                             \
        _Pragma("unroll")                                                       \
        for (int j_ = 0; j_ < 8; ++j_) pb_[j_] = f2b(sb[ks_ * 8 + j_]);         \
        *(short8*)&Blds[buf_][tid][ks_ * 8] = pb_;                              \
    }                                                                           \
} while (0)

    DO_LOADS(0);
    DO_STORE(0);
    __syncthreads();

    for (int kt = 0; kt < 192; ++kt) {
        const int cur = kt & 1;
        if (kt + 1 < 192) DO_LOADS(kt + 1);   // issue next-step globals early

        // A frags: row = wr*64 + mi*16 + l15, 8 contiguous k at q*8.
        short8 afr[4];
        #pragma unroll
        for (int mi = 0; mi < 4; ++mi)
            afr[mi] = *(const short8*)&Alds[cur][wr * 64 + mi * 16 + l15][q * 8];

        // B frags: identical pattern on the transposed-staged tile (mirrored layout
        // => correctness invariant to the MFMA's internal slot->k permutation).
        short8 bfr[4][2];
        #pragma unroll
        for (int g = 0; g < 4; ++g)
            #pragma unroll
            for (int ni = 0; ni < 2; ++ni)
                bfr[g][ni] = *(const short8*)
                    &Blds[cur][g * 64 + wc * 32 + ni * 16 + l15][q * 8];

        #pragma unroll
        for (int g = 0; g < 4; ++g)
            #pragma unroll
            for (int ni = 0; ni < 2; ++ni)
                #pragma unroll
                for (int mi = 0; mi < 4; ++mi)
                    acc[g][mi][ni] = __builtin_amdgcn_mfma_f32_16x16x32_bf16(
                        afr[mi], bfr[g][ni], acc[g][mi][ni], 0, 0, 0);

        if (kt + 1 < 192) DO_STORE(cur ^ 1);
        __syncthreads();   // single barrier/step: reads(cur) precede it, writes go to cur^1
    }

#undef DO_LOADS
#undef DO_STORE

    // Epilogue: C/D layout col = l15, row = q*4 + reg (m89/m91 HW-verified).
    #pragma unroll
    for (int ni = 0; ni < 2; ++ni) {
        const int col = col0 + wc * 32 + ni * 16 + l15;
        const float bi  = bias[col];
        const float bf_ = bias[2048 + col];
        const float bc  = bias[4096 + col];
        const float bo  = bias[6144 + col];
        #pragma unroll
        for (int mi = 0; mi < 4; ++mi) {
            const int rbase = row0 + wr * 64 + mi * 16 + q * 4;
            #pragma unroll
            for (int rr = 0; rr < 4; ++rr) {
                const int row = rbase + rr;
                const float xi = acc[0][mi][ni][rr] + bi;
                const float xf = acc[1][mi][ni][rr] + bf_;
                const float xc = acc[2][mi][ni][rr] + bc;
                const float xo = acc[3][mi][ni][rr] + bo;
                const float ig = __builtin_amdgcn_fmed3f(0.2f * xi + 0.5f, 0.f, 1.f);
                const float fg = __builtin_amdgcn_fmed3f(0.2f * xf + 0.5f, 0.f, 1.f);
                const float og = __builtin_amdgcn_fmed3f(0.2f * xo + 0.5f, 0.f, 1.f);
                const float cp = c_tm1[(long)row * 2048 + col];
                const float cc = fg * cp + ig * tanhf(xc);
                out[(long)row * 2048 + col] = og * tanhf(cc);
            }
        }
    }
}

extern "C" void kernel_launch(void* const* d_in, const int* in_sizes, int n_in,
                              void* d_out, int out_size, void* d_ws, size_t ws_size,
                              hipStream_t stream) {
    const float* xin  = (const float*)d_in[0];
    const float* h1   = (const float*)d_in[1];
    const float* c1   = (const float*)d_in[2];
    const float* z1   = (const float*)d_in[3];
    const float* Wk   = (const float*)d_in[4];
    const float* Wr   = (const float*)d_in[5];
    const float* Wl   = (const float*)d_in[6];
    const float* bias = (const float*)d_in[7];
    float* out = (float*)d_out;
    (void)in_sizes; (void)n_in; (void)out_size; (void)d_ws; (void)ws_size;

    vlstm_fused<<<dim3(1024), dim3(256), 0, stream>>>(xin, h1, c1, z1, Wk, Wr, Wl, bias, out);
}

// Round 5
// 789.561 us; speedup vs baseline: 8.4330x; 1.2305x over previous
//
#include <hip/hip_runtime.h>
#include <hip/hip_bf16.h>

typedef float f32x4 __attribute__((ext_vector_type(4)));
typedef short short8 __attribute__((ext_vector_type(8)));   // 8 bf16 = 16 B
typedef short short4v __attribute__((ext_vector_type(4)));  // 4 bf16 = 8 B

__device__ __forceinline__ short f2b(float x) {
    union { __hip_bfloat16 b; short s; } u;
    u.b = __float2bfloat16(x);   // round-to-nearest-even
    return u.s;
}

// ---------------------------------------------------------------------------
// Converter 1: A sources (inputs, h_tm1, z_tm1) fp32 -> Aws[row][kglob] bf16,
// kglob = s*2048 + kl (K-concat order matches the GEMM's source order).
// Pure elementwise, fully coalesced. 12288 blocks x 256 thr x 8 elems.
// ---------------------------------------------------------------------------
__global__ __launch_bounds__(256)
void conv_a(const float* __restrict__ x0, const float* __restrict__ x1,
            const float* __restrict__ x2, unsigned short* __restrict__ Aws)
{
    const long i = (long)blockIdx.x * 256 + threadIdx.x;   // unit = 8 elems
    const long per_src = (long)4096 * 2048 / 8;
    const int  s = (int)(i / per_src);
    const long e0 = (i % per_src) * 8;
    const int  row = (int)(e0 >> 11), kl = (int)(e0 & 2047);
    const float* src = (s == 0) ? x0 : (s == 1) ? x1 : x2;
    const f32x4 v0 = *(const f32x4*)(src + e0);
    const f32x4 v1 = *(const f32x4*)(src + e0 + 4);
    short8 p;
    #pragma unroll
    for (int j = 0; j < 4; ++j) { p[j] = f2b(v0[j]); p[4 + j] = f2b(v1[j]); }
    *(short8*)&Aws[(long)row * 6144 + s * 2048 + kl] = p;
}

// ---------------------------------------------------------------------------
// Converter 2: weights [K][8192] fp32 -> Bws[effcol][kglob] bf16 (TRANSPOSED),
// effcol = W column index (gate-major, 0..8191), kglob = s*2048 + k.
// 64k x 64e tile per block via LDS transpose. 3*32*128 = 12288 blocks.
// ---------------------------------------------------------------------------
__global__ __launch_bounds__(256)
void conv_b(const float* __restrict__ Wk, const float* __restrict__ Wr,
            const float* __restrict__ Wl, unsigned short* __restrict__ Bws)
{
    __shared__ float lt[64][65];
    const int bid = (int)blockIdx.x;
    const int s   = bid >> 12;            // /4096
    const int r   = bid & 4095;
    const int kbase = (r >> 7) * 64;      // 32 k-tiles
    const int ebase = (r & 127) * 64;     // 128 e-tiles
    const float* W = (s == 0) ? Wk : (s == 1) ? Wr : Wl;
    const int tr = threadIdx.x >> 4, tc = threadIdx.x & 15;

    #pragma unroll
    for (int p = 0; p < 4; ++p) {
        const int kr = p * 16 + tr;
        const f32x4 v = *(const f32x4*)&W[(long)(kbase + kr) * 8192 + ebase + tc * 4];
        #pragma unroll
        for (int j = 0; j < 4; ++j) lt[kr][tc * 4 + j] = v[j];
    }
    __syncthreads();
    #pragma unroll
    for (int p = 0; p < 4; ++p) {
        const int er = p * 16 + tr;
        const int k4 = tc * 4;
        short4v q;
        #pragma unroll
        for (int j = 0; j < 4; ++j) q[j] = f2b(lt[k4 + j][er]);
        *(short4v*)&Bws[(long)(ebase + er) * 6144 + (long)s * 2048 + kbase + k4] = q;
    }
}

// ---------------------------------------------------------------------------
// Main fused kernel, bf16 pre-converted operands.
// Geometry/numerics identical to round-4 (absmax 1.733e-2 banked):
// 128 rows x 64 h-cols block tile, 4 waves, BK=32, double-buffered LDS,
// mirrored k-contiguous A/B layouts (stride 40), mfma_16x16x32_bf16.
// Hot loop now: A = 2x16B loads, B = 4x16B contiguous loads, no cvt.
// ---------------------------------------------------------------------------
__global__ __launch_bounds__(256, 2)
void vlstm_fused_bf16(const unsigned short* __restrict__ Aws,
                      const unsigned short* __restrict__ Bws,
                      const float* __restrict__ c_tm1,
                      const float* __restrict__ bias,
                      float* __restrict__ out)
{
    __shared__ __align__(16) unsigned short Alds[2][128][40];   // 20 KB
    __shared__ __align__(16) unsigned short Blds[2][256][40];   // 40 KB

    const int tid  = threadIdx.x;
    const int wave = tid >> 6, lane = tid & 63;
    const int wr = wave >> 1, wc = wave & 1;
    const int l15 = lane & 15, q = lane >> 4;

    const int bid = (int)blockIdx.x;
    const int swz = (bid & 7) * 128 + (bid >> 3);   // XCD-bijective (1024%8==0)
    const int bm = swz >> 5, bn = swz & 31;
    const int row0 = bm * 128, col0 = bn * 64;

    const int arow = tid >> 1, kh = tid & 1;        // A: 2 thr/row, 16 k each
    const long a_off = (long)(row0 + arow) * 6144 + kh * 16;
    const long b_off = (long)((tid >> 6) * 2048 + col0 + (tid & 63)) * 6144;

    f32x4 acc[4][4][2];
    #pragma unroll
    for (int g = 0; g < 4; ++g)
        #pragma unroll
        for (int mi = 0; mi < 4; ++mi)
            #pragma unroll
            for (int ni = 0; ni < 2; ++ni)
                acc[g][mi][ni] = (f32x4){0.f, 0.f, 0.f, 0.f};

    short8 sa0, sa1, sbv[4];

#define DO_LOADS(kn_) do {                                                      \
    const short8* ap_ = (const short8*)(Aws + a_off + (kn_) * 32);              \
    sa0 = ap_[0]; sa1 = ap_[1];                                                 \
    const short8* bp_ = (const short8*)(Bws + b_off + (kn_) * 32);              \
    _Pragma("unroll")                                                           \
    for (int ks_ = 0; ks_ < 4; ++ks_) sbv[ks_] = bp_[ks_];                      \
} while (0)

#define DO_STORE(buf_) do {                                                     \
    *(short8*)&Alds[buf_][arow][kh * 16]     = sa0;                             \
    *(short8*)&Alds[buf_][arow][kh * 16 + 8] = sa1;                             \
    _Pragma("unroll")                                                           \
    for (int ks_ = 0; ks_ < 4; ++ks_)                                           \
        *(short8*)&Blds[buf_][tid][ks_ * 8] = sbv[ks_];                         \
} while (0)

    DO_LOADS(0);
    DO_STORE(0);
    __syncthreads();

    for (int kt = 0; kt < 192; ++kt) {
        const int cur = kt & 1;
        if (kt + 1 < 192) DO_LOADS(kt + 1);

        short8 afr[4];
        #pragma unroll
        for (int mi = 0; mi < 4; ++mi)
            afr[mi] = *(const short8*)&Alds[cur][wr * 64 + mi * 16 + l15][q * 8];

        short8 bfr[4][2];
        #pragma unroll
        for (int g = 0; g < 4; ++g)
            #pragma unroll
            for (int ni = 0; ni < 2; ++ni)
                bfr[g][ni] = *(const short8*)
                    &Blds[cur][g * 64 + wc * 32 + ni * 16 + l15][q * 8];

        #pragma unroll
        for (int g = 0; g < 4; ++g)
            #pragma unroll
            for (int ni = 0; ni < 2; ++ni)
                #pragma unroll
                for (int mi = 0; mi < 4; ++mi)
                    acc[g][mi][ni] = __builtin_amdgcn_mfma_f32_16x16x32_bf16(
                        afr[mi], bfr[g][ni], acc[g][mi][ni], 0, 0, 0);

        if (kt + 1 < 192) DO_STORE(cur ^ 1);
        __syncthreads();
    }

#undef DO_LOADS
#undef DO_STORE

    // Epilogue: C/D layout col = l15, row = q*4 + reg (m89/m91 HW-verified).
    #pragma unroll
    for (int ni = 0; ni < 2; ++ni) {
        const int col = col0 + wc * 32 + ni * 16 + l15;
        const float bi  = bias[col];
        const float bf_ = bias[2048 + col];
        const float bc  = bias[4096 + col];
        const float bo  = bias[6144 + col];
        #pragma unroll
        for (int mi = 0; mi < 4; ++mi) {
            const int rbase = row0 + wr * 64 + mi * 16 + q * 4;
            #pragma unroll
            for (int rr = 0; rr < 4; ++rr) {
                const int row = rbase + rr;
                const float xi = acc[0][mi][ni][rr] + bi;
                const float xf = acc[1][mi][ni][rr] + bf_;
                const float xc = acc[2][mi][ni][rr] + bc;
                const float xo = acc[3][mi][ni][rr] + bo;
                const float ig = __builtin_amdgcn_fmed3f(0.2f * xi + 0.5f, 0.f, 1.f);
                const float fg = __builtin_amdgcn_fmed3f(0.2f * xf + 0.5f, 0.f, 1.f);
                const float og = __builtin_amdgcn_fmed3f(0.2f * xo + 0.5f, 0.f, 1.f);
                const float cp = c_tm1[(long)row * 2048 + col];
                const float cc = fg * cp + ig * tanhf(xc);
                out[(long)row * 2048 + col] = og * tanhf(cc);
            }
        }
    }
}

// ---------------------------------------------------------------------------
// Legacy fallback (round-4 kernel, verbatim): used only if ws_size is too
// small for the bf16 staging buffers. Guarantees no regression.
// ---------------------------------------------------------------------------
__global__ __launch_bounds__(256, 2)
void vlstm_fused_legacy(const float* __restrict__ xin, const float* __restrict__ h_tm1,
                        const float* __restrict__ c_tm1, const float* __restrict__ z_tm1,
                        const float* __restrict__ Wk, const float* __restrict__ Wr,
                        const float* __restrict__ Wl, const float* __restrict__ bias,
                        float* __restrict__ out)
{
    __shared__ __align__(16) unsigned short Alds[2][128][40];
    __shared__ __align__(16) unsigned short Blds[2][256][40];

    const int tid  = threadIdx.x;
    const int wave = tid >> 6, lane = tid & 63;
    const int wr = wave >> 1, wc = wave & 1;
    const int l15 = lane & 15, q = lane >> 4;

    const int bid = (int)blockIdx.x;
    const int swz = (bid & 7) * 128 + (bid >> 3);
    const int bm = swz >> 5, bn = swz & 31;
    const int row0 = bm * 128, col0 = bn * 64;

    const int arow = tid >> 1, kh = tid & 1;
    const long bg_off = (long)(tid >> 6) * 2048 + col0 + (tid & 63);

    f32x4 acc[4][4][2];
    #pragma unroll
    for (int g = 0; g < 4; ++g)
        #pragma unroll
        for (int mi = 0; mi < 4; ++mi)
            #pragma unroll
            for (int ni = 0; ni < 2; ++ni)
                acc[g][mi][ni] = (f32x4){0.f, 0.f, 0.f, 0.f};

    f32x4 sa[4];
    float sb[32];

#define DO_LOADS_L(kn_) do {                                                    \
    const int s_  = (kn_) >> 6;                                                 \
    const int kl_ = ((kn_) & 63) << 5;                                          \
    const float* Ap_ = (s_ == 0) ? xin : (s_ == 1) ? h_tm1 : z_tm1;             \
    const float* Bp_ = (s_ == 0) ? Wk  : (s_ == 1) ? Wr    : Wl;                \
    const float* ap_ = Ap_ + (long)(row0 + arow) * 2048 + kl_ + kh * 16;        \
    _Pragma("unroll")                                                           \
    for (int i_ = 0; i_ < 4; ++i_) sa[i_] = ((const f32x4*)ap_)[i_];            \
    const float* bp_ = Bp_ + (long)kl_ * 8192 + bg_off;                         \
    _Pragma("unroll")                                                           \
    for (int kk_ = 0; kk_ < 32; ++kk_) sb[kk_] = bp_[(long)kk_ * 8192];         \
} while (0)

#define DO_STORE_L(buf_) do {                                                   \
    short8 p0_, p1_;                                                            \
    _Pragma("unroll")                                                           \
    for (int j_ = 0; j_ < 4; ++j_) {                                            \
        p0_[j_] = f2b(sa[0][j_]); p0_[4 + j_] = f2b(sa[1][j_]);                 \
        p1_[j_] = f2b(sa[2][j_]); p1_[4 + j_] = f2b(sa[3][j_]);                 \
    }                                                                           \
    *(short8*)&Alds[buf_][arow][kh * 16]     = p0_;                             \
    *(short8*)&Alds[buf_][arow][kh * 16 + 8] = p1_;                             \
    _Pragma("unroll")                                                           \
    for (int ks_ = 0; ks_ < 4; ++ks_) {                                         \
        short8 pb_;                                                             \
        _Pragma("unroll")                                                       \
        for (int j_ = 0; j_ < 8; ++j_) pb_[j_] = f2b(sb[ks_ * 8 + j_]);         \
        *(short8*)&Blds[buf_][tid][ks_ * 8] = pb_;                              \
    }                                                                           \
} while (0)

    DO_LOADS_L(0);
    DO_STORE_L(0);
    __syncthreads();

    for (int kt = 0; kt < 192; ++kt) {
        const int cur = kt & 1;
        if (kt + 1 < 192) DO_LOADS_L(kt + 1);

        short8 afr[4];
        #pragma unroll
        for (int mi = 0; mi < 4; ++mi)
            afr[mi] = *(const short8*)&Alds[cur][wr * 64 + mi * 16 + l15][q * 8];

        short8 bfr[4][2];
        #pragma unroll
        for (int g = 0; g < 4; ++g)
            #pragma unroll
            for (int ni = 0; ni < 2; ++ni)
                bfr[g][ni] = *(const short8*)
                    &Blds[cur][g * 64 + wc * 32 + ni * 16 + l15][q * 8];

        #pragma unroll
        for (int g = 0; g < 4; ++g)
            #pragma unroll
            for (int ni = 0; ni < 2; ++ni)
                #pragma unroll
                for (int mi = 0; mi < 4; ++mi)
                    acc[g][mi][ni] = __builtin_amdgcn_mfma_f32_16x16x32_bf16(
                        afr[mi], bfr[g][ni], acc[g][mi][ni], 0, 0, 0);

        if (kt + 1 < 192) DO_STORE_L(cur ^ 1);
        __syncthreads();
    }

#undef DO_LOADS_L
#undef DO_STORE_L

    #pragma unroll
    for (int ni = 0; ni < 2; ++ni) {
        const int col = col0 + wc * 32 + ni * 16 + l15;
        const float bi  = bias[col];
        const float bf_ = bias[2048 + col];
        const float bc  = bias[4096 + col];
        const float bo  = bias[6144 + col];
        #pragma unroll
        for (int mi = 0; mi < 4; ++mi) {
            const int rbase = row0 + wr * 64 + mi * 16 + q * 4;
            #pragma unroll
            for (int rr = 0; rr < 4; ++rr) {
                const int row = rbase + rr;
                const float xi = acc[0][mi][ni][rr] + bi;
                const float xf = acc[1][mi][ni][rr] + bf_;
                const float xc = acc[2][mi][ni][rr] + bc;
                const float xo = acc[3][mi][ni][rr] + bo;
                const float ig = __builtin_amdgcn_fmed3f(0.2f * xi + 0.5f, 0.f, 1.f);
                const float fg = __builtin_amdgcn_fmed3f(0.2f * xf + 0.5f, 0.f, 1.f);
                const float og = __builtin_amdgcn_fmed3f(0.2f * xo + 0.5f, 0.f, 1.f);
                const float cp = c_tm1[(long)row * 2048 + col];
                const float cc = fg * cp + ig * tanhf(xc);
                out[(long)row * 2048 + col] = og * tanhf(cc);
            }
        }
    }
}

extern "C" void kernel_launch(void* const* d_in, const int* in_sizes, int n_in,
                              void* d_out, int out_size, void* d_ws, size_t ws_size,
                              hipStream_t stream) {
    const float* xin  = (const float*)d_in[0];
    const float* h1   = (const float*)d_in[1];
    const float* c1   = (const float*)d_in[2];
    const float* z1   = (const float*)d_in[3];
    const float* Wk   = (const float*)d_in[4];
    const float* Wr   = (const float*)d_in[5];
    const float* Wl   = (const float*)d_in[6];
    const float* bias = (const float*)d_in[7];
    float* out = (float*)d_out;
    (void)in_sizes; (void)n_in; (void)out_size;

    const size_t a_elems = (size_t)4096 * 6144;        // 25,165,824
    const size_t b_elems = (size_t)8192 * 6144;        // 50,331,648
    const size_t need = (a_elems + b_elems) * 2;       // 150,994,944 B

    if (ws_size >= need) {
        unsigned short* Aws = (unsigned short*)d_ws;
        unsigned short* Bws = Aws + a_elems;
        conv_a<<<dim3(12288), dim3(256), 0, stream>>>(xin, h1, z1, Aws);
        conv_b<<<dim3(12288), dim3(256), 0, stream>>>(Wk, Wr, Wl, Bws);
        vlstm_fused_bf16<<<dim3(1024), dim3(256), 0, stream>>>(Aws, Bws, c1, bias, out);
    } else {
        vlstm_fused_legacy<<<dim3(1024), dim3(256), 0, stream>>>(
            xin, h1, c1, z1, Wk, Wr, Wl, bias, out);
    }
}

// Round 6
// 552.049 us; speedup vs baseline: 12.0612x; 1.4302x over previous
//
#include <hip/hip_runtime.h>
#include <hip/hip_bf16.h>

typedef float f32x4 __attribute__((ext_vector_type(4)));
typedef short short8 __attribute__((ext_vector_type(8)));   // 8 bf16 = 16 B
typedef short short4v __attribute__((ext_vector_type(4)));  // 4 bf16 = 8 B

__device__ __forceinline__ short f2b(float x) {
    union { __hip_bfloat16 b; short s; } u;
    u.b = __float2bfloat16(x);   // round-to-nearest-even
    return u.s;
}

// async global->LDS, 16 B per lane; LDS dest is wave-uniform base + lane*16.
__device__ __forceinline__ void gload16(const void* g, void* l) {
    __builtin_amdgcn_global_load_lds(
        (const __attribute__((address_space(1))) unsigned int*)g,
        (__attribute__((address_space(3))) unsigned int*)l, 16, 0, 0);
}

// ---------------------------------------------------------------------------
// Converter 1 (unchanged from round 5): A sources fp32 -> Aws[row][kglob] bf16.
// ---------------------------------------------------------------------------
__global__ __launch_bounds__(256)
void conv_a(const float* __restrict__ x0, const float* __restrict__ x1,
            const float* __restrict__ x2, unsigned short* __restrict__ Aws)
{
    const long i = (long)blockIdx.x * 256 + threadIdx.x;   // unit = 8 elems
    const long per_src = (long)4096 * 2048 / 8;
    const int  s = (int)(i / per_src);
    const long e0 = (i % per_src) * 8;
    const int  row = (int)(e0 >> 11), kl = (int)(e0 & 2047);
    const float* src = (s == 0) ? x0 : (s == 1) ? x1 : x2;
    const f32x4 v0 = *(const f32x4*)(src + e0);
    const f32x4 v1 = *(const f32x4*)(src + e0 + 4);
    short8 p;
    #pragma unroll
    for (int j = 0; j < 4; ++j) { p[j] = f2b(v0[j]); p[4 + j] = f2b(v1[j]); }
    *(short8*)&Aws[(long)row * 6144 + s * 2048 + kl] = p;
}

// ---------------------------------------------------------------------------
// Converter 2 (unchanged from round 5): weights fp32 -> Bws[effcol][kglob] bf16
// (transposed), effcol = gate*2048 + hcol.
// ---------------------------------------------------------------------------
__global__ __launch_bounds__(256)
void conv_b(const float* __restrict__ Wk, const float* __restrict__ Wr,
            const float* __restrict__ Wl, unsigned short* __restrict__ Bws)
{
    __shared__ float lt[64][65];
    const int bid = (int)blockIdx.x;
    const int s   = bid >> 12;
    const int r   = bid & 4095;
    const int kbase = (r >> 7) * 64;
    const int ebase = (r & 127) * 64;
    const float* W = (s == 0) ? Wk : (s == 1) ? Wr : Wl;
    const int tr = threadIdx.x >> 4, tc = threadIdx.x & 15;

    #pragma unroll
    for (int p = 0; p < 4; ++p) {
        const int kr = p * 16 + tr;
        const f32x4 v = *(const f32x4*)&W[(long)(kbase + kr) * 8192 + ebase + tc * 4];
        #pragma unroll
        for (int j = 0; j < 4; ++j) lt[kr][tc * 4 + j] = v[j];
    }
    __syncthreads();
    #pragma unroll
    for (int p = 0; p < 4; ++p) {
        const int er = p * 16 + tr;
        const int k4 = tc * 4;
        short4v qv;
        #pragma unroll
        for (int j = 0; j < 4; ++j) qv[j] = f2b(lt[k4 + j][er]);
        *(short4v*)&Bws[(long)(ebase + er) * 6144 + (long)s * 2048 + kbase + k4] = qv;
    }
}

// ---------------------------------------------------------------------------
// Main GEMM+epilogue: counted-vmcnt 2-phase/K-tile schedule, global_load_lds
// staging, XOR-swizzled LDS, raw s_barrier (no vmcnt-draining __syncthreads).
// Tile: 128 rows x 32 hcols (=128 effcols as [gate][hcol] rows in B-LDS).
// BK=64 (2 mfma k-halves). 4 waves (2M x 2N). LDS exactly 64 KB.
// K-accumulation order bit-identical to round 5 -> absmax 1.733e-2 expected.
// ---------------------------------------------------------------------------
__global__ __launch_bounds__(256, 2)
void vlstm_gemm8(const unsigned short* __restrict__ Aws,
                 const unsigned short* __restrict__ Bws,
                 const float* __restrict__ c_tm1,
                 const float* __restrict__ bias,
                 float* __restrict__ out)
{
    __shared__ __align__(16) unsigned short lds[2][2][128][64];  // [buf][A/B][row][k] = 64 KB

    const int tid  = threadIdx.x;
    const int w    = tid >> 6, lane = tid & 63;
    const int wm   = w >> 1,  wn   = w & 1;
    const int l15  = lane & 15, q = lane >> 4;
    const int lrow = lane >> 3;                 // staging: row within 8-row chunk
    const int lsw  = (lane & 7) ^ lrow;         // staging: swizzled source octet
    const int oq   = q ^ (l15 & 7);             // read: swizzled octet base

    const int bid = (int)blockIdx.x;
    const int swz = (bid & 7) * 256 + (bid >> 3);   // XCD-bijective (2048 % 8 == 0)
    const int bm  = swz >> 6, bn = swz & 63;
    const int row0 = bm * 128, c0 = bn * 32;        // c0 in hcols

    // staging source bases (element offsets); add j-stride and t*64 per instr
    const long a_src0 = (long)(row0 + w * 32 + lrow) * 6144 + lsw * 8;
    const long b_src0 = (long)(c0 + w * 8 + lrow) * 6144 + lsw * 8;   // + j*2048*6144

    f32x4 acc[4][4];            // [mi][gate]
    #pragma unroll
    for (int mi = 0; mi < 4; ++mi)
        #pragma unroll
        for (int g = 0; g < 4; ++g)
            acc[mi][g] = (f32x4){0.f, 0.f, 0.f, 0.f};

    short8 afr[4][2];           // [mi][k-half]
    short8 bfr[4][2];           // [gate][k-half]

#define STAGE_A(buf_, t_) do { _Pragma("unroll")                                 \
    for (int j_ = 0; j_ < 4; ++j_)                                               \
        gload16(Aws + a_src0 + (long)j_ * (8 * 6144) + (t_) * 64,                \
                &lds[buf_][0][w * 32 + j_ * 8][0]); } while (0)

#define STAGE_B(buf_, t_) do { _Pragma("unroll")                                 \
    for (int j_ = 0; j_ < 4; ++j_)   /* j_ = gate; gate-ascending issue order */ \
        gload16(Bws + b_src0 + (long)j_ * (2048 * 6144) + (t_) * 64,             \
                &lds[buf_][1][j_ * 32 + w * 8][0]); } while (0)

#define LOAD_AFR(cur_) do { _Pragma("unroll")                                    \
    for (int mi_ = 0; mi_ < 4; ++mi_) { _Pragma("unroll")                        \
        for (int h_ = 0; h_ < 2; ++h_)                                           \
            afr[mi_][h_] = *(const short8*)                                      \
                &lds[cur_][0][wm * 64 + mi_ * 16 + l15][(oq ^ (h_ << 2)) * 8];   \
    } } while (0)

#define LOAD_BFR(cur_, glo_) do { _Pragma("unroll")                              \
    for (int g_ = 0; g_ < 2; ++g_) { _Pragma("unroll")                           \
        for (int h_ = 0; h_ < 2; ++h_)                                           \
            bfr[(glo_) + g_][h_] = *(const short8*)                              \
                &lds[cur_][1][((glo_) + g_) * 32 + wn * 16 + l15]                \
                             [(oq ^ (h_ << 2)) * 8];                             \
    } } while (0)

#define MFMA_Q(glo_) do {                                                        \
    __builtin_amdgcn_s_setprio(1);                                               \
    _Pragma("unroll")                                                            \
    for (int h_ = 0; h_ < 2; ++h_) { _Pragma("unroll")                           \
        for (int mi_ = 0; mi_ < 4; ++mi_) { _Pragma("unroll")                    \
            for (int g_ = 0; g_ < 2; ++g_)                                       \
                acc[mi_][(glo_) + g_] = __builtin_amdgcn_mfma_f32_16x16x32_bf16( \
                    afr[mi_][h_], bfr[(glo_) + g_][h_], acc[mi_][(glo_) + g_],   \
                    0, 0, 0); } }                                                \
    __builtin_amdgcn_s_setprio(0); } while (0)

    // Prologue: stage tile 0 fully, drain, barrier.
    STAGE_A(0, 0);
    STAGE_B(0, 0);
    asm volatile("s_waitcnt vmcnt(0)" ::: "memory");
    __builtin_amdgcn_s_barrier();
    __builtin_amdgcn_sched_barrier(0);

    for (int t = 0; t < 95; ++t) {
        const int cur = t & 1;
        // ---- phase 1: stage A(t+1); compute gates 0-1 of tile t ----
        STAGE_A(cur ^ 1, t + 1);
        LOAD_AFR(cur);
        LOAD_BFR(cur, 0);
        MFMA_Q(0);
        // guard B(t) gates 2-3 (issued last iter ph2, j=2,3): outstanding =
        // B(t)g23(2 oldest) + A(t+1)(4) = 6 -> vmcnt(4) waits the 2 oldest.
        asm volatile("s_waitcnt vmcnt(4)" ::: "memory");
        __builtin_amdgcn_s_barrier();
        __builtin_amdgcn_sched_barrier(0);
        // ---- phase 2: stage B(t+1); compute gates 2-3 of tile t ----
        STAGE_B(cur ^ 1, t + 1);
        LOAD_BFR(cur, 2);
        MFMA_Q(2);
        // guard A(t+1) + B(t+1) gates 0-1 for next ph1: outstanding =
        // A(t+1)(4) + B(t+1)(4) = 8 -> vmcnt(2) waits the 6 oldest.
        asm volatile("s_waitcnt vmcnt(2)" ::: "memory");
        __builtin_amdgcn_s_barrier();
        __builtin_amdgcn_sched_barrier(0);
    }
    {   // peeled last tile t = 95 (no staging; full drain before gates 2-3)
        const int cur = 95 & 1;
        LOAD_AFR(cur);
        LOAD_BFR(cur, 0);
        MFMA_Q(0);
        asm volatile("s_waitcnt vmcnt(0)" ::: "memory");
        __builtin_amdgcn_s_barrier();
        __builtin_amdgcn_sched_barrier(0);
        LOAD_BFR(cur, 2);
        MFMA_Q(2);
    }

#undef STAGE_A
#undef STAGE_B
#undef LOAD_AFR
#undef LOAD_BFR
#undef MFMA_Q

    // Epilogue: C/D layout col = l15, row = q*4 + rr (m89/m91 HW-verified).
    // One hcol per lane; gates are the acc's second index -> lane-local algebra.
    {
        const int col = c0 + wn * 16 + l15;
        const float bi  = bias[col];
        const float bf_ = bias[2048 + col];
        const float bc  = bias[4096 + col];
        const float bo  = bias[6144 + col];
        #pragma unroll
        for (int mi = 0; mi < 4; ++mi) {
            const int rbase = row0 + wm * 64 + mi * 16 + q * 4;
            #pragma unroll
            for (int rr = 0; rr < 4; ++rr) {
                const int row = rbase + rr;
                const float xi = acc[mi][0][rr] + bi;
                const float xf = acc[mi][1][rr] + bf_;
                const float xc = acc[mi][2][rr] + bc;
                const float xo = acc[mi][3][rr] + bo;
                const float ig = __builtin_amdgcn_fmed3f(0.2f * xi + 0.5f, 0.f, 1.f);
                const float fg = __builtin_amdgcn_fmed3f(0.2f * xf + 0.5f, 0.f, 1.f);
                const float og = __builtin_amdgcn_fmed3f(0.2f * xo + 0.5f, 0.f, 1.f);
                const float cp = c_tm1[(long)row * 2048 + col];
                const float cc = fg * cp + ig * tanhf(xc);
                out[(long)row * 2048 + col] = og * tanhf(cc);
            }
        }
    }
}

// ---------------------------------------------------------------------------
// Legacy fallback (round-4 kernel, verbatim): only if ws_size is too small.
// ---------------------------------------------------------------------------
__global__ __launch_bounds__(256, 2)
void vlstm_fused_legacy(const float* __restrict__ xin, const float* __restrict__ h_tm1,
                        const float* __restrict__ c_tm1, const float* __restrict__ z_tm1,
                        const float* __restrict__ Wk, const float* __restrict__ Wr,
                        const float* __restrict__ Wl, const float* __restrict__ bias,
                        float* __restrict__ out)
{
    __shared__ __align__(16) unsigned short Alds[2][128][40];
    __shared__ __align__(16) unsigned short Blds[2][256][40];

    const int tid  = threadIdx.x;
    const int wave = tid >> 6, lane = tid & 63;
    const int wr = wave >> 1, wc = wave & 1;
    const int l15 = lane & 15, q = lane >> 4;

    const int bid = (int)blockIdx.x;
    const int swz = (bid & 7) * 128 + (bid >> 3);
    const int bm = swz >> 5, bn = swz & 31;
    const int row0 = bm * 128, col0 = bn * 64;

    const int arow = tid >> 1, kh = tid & 1;
    const long bg_off = (long)(tid >> 6) * 2048 + col0 + (tid & 63);

    f32x4 acc[4][4][2];
    #pragma unroll
    for (int g = 0; g < 4; ++g)
        #pragma unroll
        for (int mi = 0; mi < 4; ++mi)
            #pragma unroll
            for (int ni = 0; ni < 2; ++ni)
                acc[g][mi][ni] = (f32x4){0.f, 0.f, 0.f, 0.f};

    f32x4 sa[4];
    float sb[32];

#define DO_LOADS_L(kn_) do {                                                    \
    const int s_  = (kn_) >> 6;                                                 \
    const int kl_ = ((kn_) & 63) << 5;                                          \
    const float* Ap_ = (s_ == 0) ? xin : (s_ == 1) ? h_tm1 : z_tm1;             \
    const float* Bp_ = (s_ == 0) ? Wk  : (s_ == 1) ? Wr    : Wl;                \
    const float* ap_ = Ap_ + (long)(row0 + arow) * 2048 + kl_ + kh * 16;        \
    _Pragma("unroll")                                                           \
    for (int i_ = 0; i_ < 4; ++i_) sa[i_] = ((const f32x4*)ap_)[i_];            \
    const float* bp_ = Bp_ + (long)kl_ * 8192 + bg_off;                         \
    _Pragma("unroll")                                                           \
    for (int kk_ = 0; kk_ < 32; ++kk_) sb[kk_] = bp_[(long)kk_ * 8192];         \
} while (0)

#define DO_STORE_L(buf_) do {                                                   \
    short8 p0_, p1_;                                                            \
    _Pragma("unroll")                                                           \
    for (int j_ = 0; j_ < 4; ++j_) {                                            \
        p0_[j_] = f2b(sa[0][j_]); p0_[4 + j_] = f2b(sa[1][j_]);                 \
        p1_[j_] = f2b(sa[2][j_]); p1_[4 + j_] = f2b(sa[3][j_]);                 \
    }                                                                           \
    *(short8*)&Alds[buf_][arow][kh * 16]     = p0_;                             \
    *(short8*)&Alds[buf_][arow][kh * 16 + 8] = p1_;                             \
    _Pragma("unroll")                                                           \
    for (int ks_ = 0; ks_ < 4; ++ks_) {                                         \
        short8 pb_;                                                             \
        _Pragma("unroll")                                                       \
        for (int j_ = 0; j_ < 8; ++j_) pb_[j_] = f2b(sb[ks_ * 8 + j_]);         \
        *(short8*)&Blds[buf_][tid][ks_ * 8] = pb_;                              \
    }                                                                           \
} while (0)

    DO_LOADS_L(0);
    DO_STORE_L(0);
    __syncthreads();

    for (int kt = 0; kt < 192; ++kt) {
        const int cur = kt & 1;
        if (kt + 1 < 192) DO_LOADS_L(kt + 1);

        short8 afr[4];
        #pragma unroll
        for (int mi = 0; mi < 4; ++mi)
            afr[mi] = *(const short8*)&Alds[cur][wr * 64 + mi * 16 + l15][q * 8];

        short8 bfr[4][2];
        #pragma unroll
        for (int g = 0; g < 4; ++g)
            #pragma unroll
            for (int ni = 0; ni < 2; ++ni)
                bfr[g][ni] = *(const short8*)
                    &Blds[cur][g * 64 + wc * 32 + ni * 16 + l15][q * 8];

        #pragma unroll
        for (int g = 0; g < 4; ++g)
            #pragma unroll
            for (int ni = 0; ni < 2; ++ni)
                #pragma unroll
                for (int mi = 0; mi < 4; ++mi)
                    acc[g][mi][ni] = __builtin_amdgcn_mfma_f32_16x16x32_bf16(
                        afr[mi], bfr[g][ni], acc[g][mi][ni], 0, 0, 0);

        if (kt + 1 < 192) DO_STORE_L(cur ^ 1);
        __syncthreads();
    }

#undef DO_LOADS_L
#undef DO_STORE_L

    #pragma unroll
    for (int ni = 0; ni < 2; ++ni) {
        const int col = col0 + wc * 32 + ni * 16 + l15;
        const float bi  = bias[col];
        const float bf_ = bias[2048 + col];
        const float bc  = bias[4096 + col];
        const float bo  = bias[6144 + col];
        #pragma unroll
        for (int mi = 0; mi < 4; ++mi) {
            const int rbase = row0 + wr * 64 + mi * 16 + q * 4;
            #pragma unroll
            for (int rr = 0; rr < 4; ++rr) {
                const int row = rbase + rr;
                const float xi = acc[0][mi][ni][rr] + bi;
                const float xf = acc[1][mi][ni][rr] + bf_;
                const float xc = acc[2][mi][ni][rr] + bc;
                const float xo = acc[3][mi][ni][rr] + bo;
                const float ig = __builtin_amdgcn_fmed3f(0.2f * xi + 0.5f, 0.f, 1.f);
                const float fg = __builtin_amdgcn_fmed3f(0.2f * xf + 0.5f, 0.f, 1.f);
                const float og = __builtin_amdgcn_fmed3f(0.2f * xo + 0.5f, 0.f, 1.f);
                const float cp = c_tm1[(long)row * 2048 + col];
                const float cc = fg * cp + ig * tanhf(xc);
                out[(long)row * 2048 + col] = og * tanhf(cc);
            }
        }
    }
}

extern "C" void kernel_launch(void* const* d_in, const int* in_sizes, int n_in,
                              void* d_out, int out_size, void* d_ws, size_t ws_size,
                              hipStream_t stream) {
    const float* xin  = (const float*)d_in[0];
    const float* h1   = (const float*)d_in[1];
    const float* c1   = (const float*)d_in[2];
    const float* z1   = (const float*)d_in[3];
    const float* Wk   = (const float*)d_in[4];
    const float* Wr   = (const float*)d_in[5];
    const float* Wl   = (const float*)d_in[6];
    const float* bias = (const float*)d_in[7];
    float* out = (float*)d_out;
    (void)in_sizes; (void)n_in; (void)out_size;

    const size_t a_elems = (size_t)4096 * 6144;
    const size_t b_elems = (size_t)8192 * 6144;
    const size_t need = (a_elems + b_elems) * 2;       // ~151 MB

    if (ws_size >= need) {
        unsigned short* Aws = (unsigned short*)d_ws;
        unsigned short* Bws = Aws + a_elems;
        conv_a<<<dim3(12288), dim3(256), 0, stream>>>(xin, h1, z1, Aws);
        conv_b<<<dim3(12288), dim3(256), 0, stream>>>(Wk, Wr, Wl, Bws);
        // grid: 32 m-blocks x 64 hcol-blocks = 2048
        vlstm_gemm8<<<dim3(2048), dim3(256), 0, stream>>>(Aws, Bws, c1, bias, out);
    } else {
        vlstm_fused_legacy<<<dim3(1024), dim3(256), 0, stream>>>(
            xin, h1, c1, z1, Wk, Wr, Wl, bias, out);
    }
}

// Round 7
// 508.309 us; speedup vs baseline: 13.0991x; 1.0860x over previous
//
#include <hip/hip_runtime.h>
#include <hip/hip_bf16.h>

typedef float f32x4 __attribute__((ext_vector_type(4)));
typedef short short8 __attribute__((ext_vector_type(8)));   // 8 bf16 = 16 B
typedef short short4v __attribute__((ext_vector_type(4)));  // 4 bf16 = 8 B

__device__ __forceinline__ short f2b(float x) {
    union { __hip_bfloat16 b; short s; } u;
    u.b = __float2bfloat16(x);   // round-to-nearest-even
    return u.s;
}

// async global->LDS, 16 B per lane; LDS dest is wave-uniform base + lane*16.
__device__ __forceinline__ void gload16(const void* g, void* l) {
    __builtin_amdgcn_global_load_lds(
        (const __attribute__((address_space(1))) unsigned int*)g,
        (__attribute__((address_space(3))) unsigned int*)l, 16, 0, 0);
}

// ---------------------------------------------------------------------------
// Converter 1: A sources fp32 -> Aws[row][kglob] bf16 (kglob = s*2048+k).
// ---------------------------------------------------------------------------
__global__ __launch_bounds__(256)
void conv_a(const float* __restrict__ x0, const float* __restrict__ x1,
            const float* __restrict__ x2, unsigned short* __restrict__ Aws)
{
    const long i = (long)blockIdx.x * 256 + threadIdx.x;   // unit = 8 elems
    const long per_src = (long)4096 * 2048 / 8;
    const int  s = (int)(i / per_src);
    const long e0 = (i % per_src) * 8;
    const int  row = (int)(e0 >> 11), kl = (int)(e0 & 2047);
    const float* src = (s == 0) ? x0 : (s == 1) ? x1 : x2;
    const f32x4 v0 = *(const f32x4*)(src + e0);
    const f32x4 v1 = *(const f32x4*)(src + e0 + 4);
    short8 p;
    #pragma unroll
    for (int j = 0; j < 4; ++j) { p[j] = f2b(v0[j]); p[4 + j] = f2b(v1[j]); }
    *(short8*)&Aws[(long)row * 6144 + s * 2048 + kl] = p;
}

// ---------------------------------------------------------------------------
// Converter 2: weights fp32 -> Bws[effcol][kglob] bf16 (transposed),
// effcol = gate*2048 + hcol.
// ---------------------------------------------------------------------------
__global__ __launch_bounds__(256)
void conv_b(const float* __restrict__ Wk, const float* __restrict__ Wr,
            const float* __restrict__ Wl, unsigned short* __restrict__ Bws)
{
    __shared__ float lt[64][65];
    const int bid = (int)blockIdx.x;
    const int s   = bid >> 12;
    const int r   = bid & 4095;
    const int kbase = (r >> 7) * 64;
    const int ebase = (r & 127) * 64;
    const float* W = (s == 0) ? Wk : (s == 1) ? Wr : Wl;
    const int tr = threadIdx.x >> 4, tc = threadIdx.x & 15;

    #pragma unroll
    for (int p = 0; p < 4; ++p) {
        const int kr = p * 16 + tr;
        const f32x4 v = *(const f32x4*)&W[(long)(kbase + kr) * 8192 + ebase + tc * 4];
        #pragma unroll
        for (int j = 0; j < 4; ++j) lt[kr][tc * 4 + j] = v[j];
    }
    __syncthreads();
    #pragma unroll
    for (int p = 0; p < 4; ++p) {
        const int er = p * 16 + tr;
        const int k4 = tc * 4;
        short4v qv;
        #pragma unroll
        for (int j = 0; j < 4; ++j) qv[j] = f2b(lt[k4 + j][er]);
        *(short4v*)&Bws[(long)(ebase + er) * 6144 + (long)s * 2048 + kbase + k4] = qv;
    }
}

// ---------------------------------------------------------------------------
// 256x256eff 4-phase/K-tile GEMM (m201-style schedule, gate-stacked B).
// BM=256 rows, BN=256 eff (gate-interleaved: B-LDS row e -> gate=(e>>4)&3,
// hcol=(e>>6)*16+(e&15)), BK=64, 512 thr / 8 waves (2M x 4N), wave tile
// 128 rows x 16 hcols x 4 gates. LDS 128 KB (2 bufs x (A 256x64 + B 256x64)).
// Per phase: {ds_read subtile | stage 1 half-tile | barrier | lgkmcnt(0) |
// setprio(1) 16 MFMA setprio(0) | barrier}; ONE vmcnt(4) per K-tile (p3).
// Staging slots (proven race-free): p0/p1 = A(t+1) halves (A free after p2),
// p2/p3 = B(t+2) halves (B free after p1); leads 3-5 phases.
// Accumulation order per acc element identical to round 6 -> absmax 1.733e-2.
// ---------------------------------------------------------------------------
__global__ __launch_bounds__(512, 2)
void vlstm_gemm256(const unsigned short* __restrict__ Aws,
                   const unsigned short* __restrict__ Bws,
                   const float* __restrict__ c_tm1,
                   const float* __restrict__ bias,
                   float* __restrict__ out)
{
    __shared__ __align__(16) unsigned short As[2][256][64];   // 64 KB
    __shared__ __align__(16) unsigned short Bs[2][256][64];   // 64 KB

    const int tid  = threadIdx.x;
    const int w    = tid >> 6, lane = tid & 63;
    const int wm   = w >> 2,  wn   = w & 3;     // 2 x 4 wave grid
    const int l15  = lane & 15, q = lane >> 4;
    const int lrow = lane >> 3;                 // staging: row within 8-row chunk
    const int lsw  = (lane & 7) ^ lrow;         // staging: swizzled source octet
    const int oq   = q ^ (l15 & 7);             // read: swizzled octet base

    const int bid = (int)blockIdx.x;
    const int swz = (bid & 7) * 64 + (bid >> 3);    // XCD-bijective (512 % 8 == 0)
    const int bm  = swz >> 5, bn = swz & 31;        // 16 x 32
    const int row0 = bm * 256, c0 = bn * 64;        // c0 in hcols

    const long a_base = (long)(row0 + w * 16 + lrow) * 6144 + lsw * 8;

    f32x4 acc[8][4];            // [mi 0..7][gate]
    #pragma unroll
    for (int mi = 0; mi < 8; ++mi)
        #pragma unroll
        for (int g = 0; g < 4; ++g)
            acc[mi][g] = (f32x4){0.f, 0.f, 0.f, 0.f};

    short8 afr[4][2];           // current mh-half: [mi_][kh]
    short8 bfr[4][2];           // all 4 gates resident: [ni][kh]

#define STAGE_A(buf_, t_, h_) do { _Pragma("unroll")                             \
    for (int j_ = 0; j_ < 2; ++j_)                                               \
        gload16(Aws + a_base + (long)((h_) * 128 + j_ * 8) * 6144                \
                    + (long)(t_) * 64,                                           \
                &As[buf_][(h_) * 128 + w * 16 + j_ * 8][0]); } while (0)

#define STAGE_B(buf_, t_, h_) do { _Pragma("unroll")                             \
    for (int j_ = 0; j_ < 2; ++j_) {                                             \
        const int e0_ = (h_) * 128 + w * 16 + j_ * 8;                            \
        const int grow_ = ((e0_ >> 4) & 3) * 2048 + c0 + (e0_ >> 6) * 16         \
                          + (e0_ & 8) + lrow;                                    \
        gload16(Bws + (long)grow_ * 6144 + lsw * 8 + (long)(t_) * 64,            \
                &Bs[buf_][e0_][0]); } } while (0)

#define LOAD_AFR(cur_, mh_) do { _Pragma("unroll")                               \
    for (int mi_ = 0; mi_ < 4; ++mi_) { _Pragma("unroll")                        \
        for (int kh_ = 0; kh_ < 2; ++kh_)                                        \
            afr[mi_][kh_] = *(const short8*)                                     \
                &As[cur_][wm * 128 + (mh_) * 64 + mi_ * 16 + l15]                \
                         [(oq ^ (kh_ << 2)) * 8]; } } while (0)

#define LOAD_BFR(cur_, nlo_) do { _Pragma("unroll")                              \
    for (int g_ = 0; g_ < 2; ++g_) { _Pragma("unroll")                           \
        for (int kh_ = 0; kh_ < 2; ++kh_)                                        \
            bfr[(nlo_) + g_][kh_] = *(const short8*)                             \
                &Bs[cur_][wn * 64 + ((nlo_) + g_) * 16 + l15]                    \
                         [(oq ^ (kh_ << 2)) * 8]; } } while (0)

#define MFMA_Q(mh_, nlo_) do {                                                   \
    __builtin_amdgcn_s_setprio(1);                                               \
    _Pragma("unroll")                                                            \
    for (int kh_ = 0; kh_ < 2; ++kh_) { _Pragma("unroll")                        \
        for (int mi_ = 0; mi_ < 4; ++mi_) { _Pragma("unroll")                    \
            for (int g_ = 0; g_ < 2; ++g_)                                       \
                acc[(mh_) * 4 + mi_][(nlo_) + g_] =                              \
                    __builtin_amdgcn_mfma_f32_16x16x32_bf16(                     \
                        afr[mi_][kh_], bfr[(nlo_) + g_][kh_],                    \
                        acc[(mh_) * 4 + mi_][(nlo_) + g_], 0, 0, 0); } }         \
    __builtin_amdgcn_s_setprio(0); } while (0)

#define PH_OPEN() do { __builtin_amdgcn_s_barrier();                             \
    asm volatile("s_waitcnt lgkmcnt(0)" ::: "memory");                           \
    __builtin_amdgcn_sched_barrier(0); } while (0)

#define PH_CLOSE() do { __builtin_amdgcn_s_barrier();                            \
    __builtin_amdgcn_sched_barrier(0); } while (0)

    // Prologue: stage A(0), B(0), B(1); wait first 4 halves; barrier.
    STAGE_A(0, 0, 0); STAGE_A(0, 0, 1);
    STAGE_B(0, 0, 0); STAGE_B(0, 0, 1);
    STAGE_B(1, 1, 0); STAGE_B(1, 1, 1);
    asm volatile("s_waitcnt vmcnt(4)" ::: "memory");
    __builtin_amdgcn_s_barrier();
    __builtin_amdgcn_sched_barrier(0);

    for (int t = 0; t < 96; ++t) {
        const int cur = t & 1, nxt = cur ^ 1;
        // ---- p0: afr(mh0) + bfr(g0,g1); stage A0(t+1); MFMA (mh0, g0-1) ----
        LOAD_AFR(cur, 0);
        LOAD_BFR(cur, 0);
        if (t + 1 < 96) STAGE_A(nxt, t + 1, 0);
        PH_OPEN();
        MFMA_Q(0, 0);
        PH_CLOSE();
        // ---- p1: bfr(g2,g3); stage A1(t+1); MFMA (mh0, g2-3) ----
        LOAD_BFR(cur, 2);
        if (t + 1 < 96) STAGE_A(nxt, t + 1, 1);
        PH_OPEN();
        MFMA_Q(0, 2);
        PH_CLOSE();
        // ---- p2: afr(mh1); stage B0(t+2) into buf cur; MFMA (mh1, g0-1) ----
        LOAD_AFR(cur, 1);
        if (t + 2 < 96) STAGE_B(cur, t + 2, 0);
        PH_OPEN();
        MFMA_Q(1, 0);
        PH_CLOSE();
        // ---- p3: stage B1(t+2); MFMA (mh1, g2-3); counted vmcnt; barrier ----
        if (t + 2 < 96) STAGE_B(cur, t + 2, 1);
        PH_OPEN();
        MFMA_Q(1, 2);
        if (t < 94) asm volatile("s_waitcnt vmcnt(4)" ::: "memory");
        else        asm volatile("s_waitcnt vmcnt(0)" ::: "memory");
        PH_CLOSE();
    }

#undef STAGE_A
#undef STAGE_B
#undef LOAD_AFR
#undef LOAD_BFR
#undef MFMA_Q
#undef PH_OPEN
#undef PH_CLOSE

    // Epilogue: C/D layout col = l15, row = q*4 + rr (m89/m91 HW-verified).
    // ni IS the gate; each lane owns hcol c0 + wn*16 + l15 -> lane-local algebra.
    {
        const int col = c0 + wn * 16 + l15;
        const float bi  = bias[col];
        const float bf_ = bias[2048 + col];
        const float bc  = bias[4096 + col];
        const float bo  = bias[6144 + col];
        #pragma unroll
        for (int mi = 0; mi < 8; ++mi) {
            const int rbase = row0 + wm * 128 + mi * 16 + q * 4;
            #pragma unroll
            for (int rr = 0; rr < 4; ++rr) {
                const int row = rbase + rr;
                const float xi = acc[mi][0][rr] + bi;
                const float xf = acc[mi][1][rr] + bf_;
                const float xc = acc[mi][2][rr] + bc;
                const float xo = acc[mi][3][rr] + bo;
                const float ig = __builtin_amdgcn_fmed3f(0.2f * xi + 0.5f, 0.f, 1.f);
                const float fg = __builtin_amdgcn_fmed3f(0.2f * xf + 0.5f, 0.f, 1.f);
                const float og = __builtin_amdgcn_fmed3f(0.2f * xo + 0.5f, 0.f, 1.f);
                const float cp = c_tm1[(long)row * 2048 + col];
                const float cc = fg * cp + ig * tanhf(xc);
                out[(long)row * 2048 + col] = og * tanhf(cc);
            }
        }
    }
}

// ---------------------------------------------------------------------------
// Legacy fallback (round-4 kernel, verbatim): only if ws_size is too small.
// ---------------------------------------------------------------------------
__global__ __launch_bounds__(256, 2)
void vlstm_fused_legacy(const float* __restrict__ xin, const float* __restrict__ h_tm1,
                        const float* __restrict__ c_tm1, const float* __restrict__ z_tm1,
                        const float* __restrict__ Wk, const float* __restrict__ Wr,
                        const float* __restrict__ Wl, const float* __restrict__ bias,
                        float* __restrict__ out)
{
    __shared__ __align__(16) unsigned short Alds[2][128][40];
    __shared__ __align__(16) unsigned short Blds[2][256][40];

    const int tid  = threadIdx.x;
    const int wave = tid >> 6, lane = tid & 63;
    const int wr = wave >> 1, wc = wave & 1;
    const int l15 = lane & 15, q = lane >> 4;

    const int bid = (int)blockIdx.x;
    const int swz = (bid & 7) * 128 + (bid >> 3);
    const int bm = swz >> 5, bn = swz & 31;
    const int row0 = bm * 128, col0 = bn * 64;

    const int arow = tid >> 1, kh = tid & 1;
    const long bg_off = (long)(tid >> 6) * 2048 + col0 + (tid & 63);

    f32x4 acc[4][4][2];
    #pragma unroll
    for (int g = 0; g < 4; ++g)
        #pragma unroll
        for (int mi = 0; mi < 4; ++mi)
            #pragma unroll
            for (int ni = 0; ni < 2; ++ni)
                acc[g][mi][ni] = (f32x4){0.f, 0.f, 0.f, 0.f};

    f32x4 sa[4];
    float sb[32];

#define DO_LOADS_L(kn_) do {                                                    \
    const int s_  = (kn_) >> 6;                                                 \
    const int kl_ = ((kn_) & 63) << 5;                                          \
    const float* Ap_ = (s_ == 0) ? xin : (s_ == 1) ? h_tm1 : z_tm1;             \
    const float* Bp_ = (s_ == 0) ? Wk  : (s_ == 1) ? Wr    : Wl;                \
    const float* ap_ = Ap_ + (long)(row0 + arow) * 2048 + kl_ + kh * 16;        \
    _Pragma("unroll")                                                           \
    for (int i_ = 0; i_ < 4; ++i_) sa[i_] = ((const f32x4*)ap_)[i_];            \
    const float* bp_ = Bp_ + (long)kl_ * 8192 + bg_off;                         \
    _Pragma("unroll")                                                           \
    for (int kk_ = 0; kk_ < 32; ++kk_) sb[kk_] = bp_[(long)kk_ * 8192];         \
} while (0)

#define DO_STORE_L(buf_) do {                                                   \
    short8 p0_, p1_;                                                            \
    _Pragma("unroll")                                                           \
    for (int j_ = 0; j_ < 4; ++j_) {                                            \
        p0_[j_] = f2b(sa[0][j_]); p0_[4 + j_] = f2b(sa[1][j_]);                 \
        p1_[j_] = f2b(sa[2][j_]); p1_[4 + j_] = f2b(sa[3][j_]);                 \
    }                                                                           \
    *(short8*)&Alds[buf_][arow][kh * 16]     = p0_;                             \
    *(short8*)&Alds[buf_][arow][kh * 16 + 8] = p1_;                             \
    _Pragma("unroll")                                                           \
    for (int ks_ = 0; ks_ < 4; ++ks_) {                                         \
        short8 pb_;                                                             \
        _Pragma("unroll")                                                       \
        for (int j_ = 0; j_ < 8; ++j_) pb_[j_] = f2b(sb[ks_ * 8 + j_]);         \
        *(short8*)&Blds[buf_][tid][ks_ * 8] = pb_;                              \
    }                                                                           \
} while (0)

    DO_LOADS_L(0);
    DO_STORE_L(0);
    __syncthreads();

    for (int kt = 0; kt < 192; ++kt) {
        const int cur = kt & 1;
        if (kt + 1 < 192) DO_LOADS_L(kt + 1);

        short8 afr[4];
        #pragma unroll
        for (int mi = 0; mi < 4; ++mi)
            afr[mi] = *(const short8*)&Alds[cur][wr * 64 + mi * 16 + l15][q * 8];

        short8 bfr[4][2];
        #pragma unroll
        for (int g = 0; g < 4; ++g)
            #pragma unroll
            for (int ni = 0; ni < 2; ++ni)
                bfr[g][ni] = *(const short8*)
                    &Blds[cur][g * 64 + wc * 32 + ni * 16 + l15][q * 8];

        #pragma unroll
        for (int g = 0; g < 4; ++g)
            #pragma unroll
            for (int ni = 0; ni < 2; ++ni)
                #pragma unroll
                for (int mi = 0; mi < 4; ++mi)
                    acc[g][mi][ni] = __builtin_amdgcn_mfma_f32_16x16x32_bf16(
                        afr[mi], bfr[g][ni], acc[g][mi][ni], 0, 0, 0);

        if (kt + 1 < 192) DO_STORE_L(cur ^ 1);
        __syncthreads();
    }

#undef DO_LOADS_L
#undef DO_STORE_L

    #pragma unroll
    for (int ni = 0; ni < 2; ++ni) {
        const int col = col0 + wc * 32 + ni * 16 + l15;
        const float bi  = bias[col];
        const float bf_ = bias[2048 + col];
        const float bc  = bias[4096 + col];
        const float bo  = bias[6144 + col];
        #pragma unroll
        for (int mi = 0; mi < 4; ++mi) {
            const int rbase = row0 + wr * 64 + mi * 16 + q * 4;
            #pragma unroll
            for (int rr = 0; rr < 4; ++rr) {
                const int row = rbase + rr;
                const float xi = acc[0][mi][ni][rr] + bi;
                const float xf = acc[1][mi][ni][rr] + bf_;
                const float xc = acc[2][mi][ni][rr] + bc;
                const float xo = acc[3][mi][ni][rr] + bo;
                const float ig = __builtin_amdgcn_fmed3f(0.2f * xi + 0.5f, 0.f, 1.f);
                const float fg = __builtin_amdgcn_fmed3f(0.2f * xf + 0.5f, 0.f, 1.f);
                const float og = __builtin_amdgcn_fmed3f(0.2f * xo + 0.5f, 0.f, 1.f);
                const float cp = c_tm1[(long)row * 2048 + col];
                const float cc = fg * cp + ig * tanhf(xc);
                out[(long)row * 2048 + col] = og * tanhf(cc);
            }
        }
    }
}

extern "C" void kernel_launch(void* const* d_in, const int* in_sizes, int n_in,
                              void* d_out, int out_size, void* d_ws, size_t ws_size,
                              hipStream_t stream) {
    const float* xin  = (const float*)d_in[0];
    const float* h1   = (const float*)d_in[1];
    const float* c1   = (const float*)d_in[2];
    const float* z1   = (const float*)d_in[3];
    const float* Wk   = (const float*)d_in[4];
    const float* Wr   = (const float*)d_in[5];
    const float* Wl   = (const float*)d_in[6];
    const float* bias = (const float*)d_in[7];
    float* out = (float*)d_out;
    (void)in_sizes; (void)n_in; (void)out_size;

    const size_t a_elems = (size_t)4096 * 6144;
    const size_t b_elems = (size_t)8192 * 6144;
    const size_t need = (a_elems + b_elems) * 2;       // ~151 MB

    if (ws_size >= need) {
        unsigned short* Aws = (unsigned short*)d_ws;
        unsigned short* Bws = Aws + a_elems;
        conv_a<<<dim3(12288), dim3(256), 0, stream>>>(xin, h1, z1, Aws);
        conv_b<<<dim3(12288), dim3(256), 0, stream>>>(Wk, Wr, Wl, Bws);
        // grid: 16 m-blocks x 32 hcol-blocks = 512
        vlstm_gemm256<<<dim3(512), dim3(512), 0, stream>>>(Aws, Bws, c1, bias, out);
    } else {
        vlstm_fused_legacy<<<dim3(1024), dim3(256), 0, stream>>>(
            xin, h1, c1, z1, Wk, Wr, Wl, bias, out);
    }
}